// Round 3
// baseline (202.379 us; speedup 1.0000x reference)
//
#include <hip/hip_runtime.h>
#include <hip/hip_bf16.h>

typedef __bf16 bf16_t;
typedef __bf16 bf16x8 __attribute__((ext_vector_type(8)));
typedef float f32x4 __attribute__((ext_vector_type(4)));

#define NTOK 49152   // s*h*w = 3*128*128 tokens per batch
#define CDIM 128
#define CHUNKS 192   // split-K chunks for the Gram
#define KT (NTOK / CHUNKS)  // 256 tokens per chunk

// 8 consecutive fp32 -> bf16x8 (round-to-nearest via cast)
__device__ inline bf16x8 load8_f32(const float* p) {
  f32x4 a = *(const f32x4*)p;
  f32x4 b = *(const f32x4*)(p + 4);
  bf16x8 r;
  r[0] = (bf16_t)a[0]; r[1] = (bf16_t)a[1]; r[2] = (bf16_t)a[2]; r[3] = (bf16_t)a[3];
  r[4] = (bf16_t)b[0]; r[5] = (bf16_t)b[1]; r[6] = (bf16_t)b[2]; r[7] = (bf16_t)b[3];
  return r;
}

// ---------------------------------------------------------------------------
// K1: per-batch token Gram S = X X^T (X is [128][49152] fp32, channel-major),
// split-K fp32 partials. Wave w owns output rows [32w,32w+32) x 128 cols.
// A/B frags of mfma_f32_16x16x32_bf16 share the lane layout
// ([m|n]=lane&15, k=(lane>>4)*8+i), so one fragment serves both roles.
// ---------------------------------------------------------------------------
__global__ __launch_bounds__(256) void k1_gram(const float* __restrict__ x,
                                               float* __restrict__ part) {
  const int b = blockIdx.x / CHUNKS, chunk = blockIdx.x % CHUNKS;
  const float* Xb = x + (size_t)b * CDIM * NTOK;
  const int tid = threadIdx.x;
  const int wave = tid >> 6, lane = tid & 63;
  const int r = lane & 15, quad = lane >> 4;

  f32x4 acc[2][8];
#pragma unroll
  for (int t = 0; t < 2; ++t)
#pragma unroll
    for (int j = 0; j < 8; ++j) acc[t][j] = (f32x4){0.f, 0.f, 0.f, 0.f};

  const int k0 = chunk * KT;
  for (int step = 0; step < KT / 32; ++step) {
    const int kc = k0 + step * 32 + quad * 8;
    bf16x8 frag[8];
#pragma unroll
    for (int g = 0; g < 8; ++g)
      frag[g] = load8_f32(Xb + (size_t)(16 * g + r) * NTOK + kc);
    bf16x8 a0 = load8_f32(Xb + (size_t)(32 * wave + r) * NTOK + kc);
    bf16x8 a1 = load8_f32(Xb + (size_t)(32 * wave + 16 + r) * NTOK + kc);
#pragma unroll
    for (int j = 0; j < 8; ++j) {
      acc[0][j] = __builtin_amdgcn_mfma_f32_16x16x32_bf16(a0, frag[j], acc[0][j], 0, 0, 0);
      acc[1][j] = __builtin_amdgcn_mfma_f32_16x16x32_bf16(a1, frag[j], acc[1][j], 0, 0, 0);
    }
  }

  float* pb = part + ((size_t)(b * CHUNKS + chunk) << 14);
#pragma unroll
  for (int t = 0; t < 2; ++t) {
#pragma unroll
    for (int j = 0; j < 8; ++j) {
#pragma unroll
      for (int reg = 0; reg < 4; ++reg) {
        const int row = 32 * wave + 16 * t + quad * 4 + reg;  // C/D: row=quad*4+reg
        const int col = 16 * j + r;                            // col=lane&15
        pb[row * 128 + col] = acc[t][j][reg];
      }
    }
  }
}

// ---------------------------------------------------------------------------
// K2: reduce 192 partials -> S[2][128][128] fp32
// ---------------------------------------------------------------------------
__global__ __launch_bounds__(256) void k2_reduce(const float* __restrict__ part,
                                                 float* __restrict__ S) {
  const int idx = blockIdx.x * 256 + threadIdx.x;  // 0..32767
  const int b = idx >> 14, elem = idx & 16383;
  const float* p = part + (((size_t)b * CHUNKS) << 14) + elem;
  float s = 0.f;
  for (int ch = 0; ch < CHUNKS; ++ch) s += p[(size_t)ch << 14];
  S[idx] = s;
}

// ---------------------------------------------------------------------------
// K3a: T[b][t][i][j] = sum_c W_t[i][c] * S_b[j][c]  (t=0:Wk, 1:Wq; S symmetric)
// ---------------------------------------------------------------------------
__global__ __launch_bounds__(256) void k3_t(const float* __restrict__ S,
                                            const float* __restrict__ Wk,
                                            const float* __restrict__ Wq,
                                            float* __restrict__ Tm) {
  const int idx = blockIdx.x * 256 + threadIdx.x;  // 0..65535
  const int j = idx & 127, i = (idx >> 7) & 127, t = (idx >> 14) & 1, b = idx >> 15;
  const float* Wrow = (t ? Wq : Wk) + i * 128;
  const float* Srow = S + (b << 14) + j * 128;
  float s = 0.f;
#pragma unroll 4
  for (int c = 0; c < 128; ++c) s += Wrow[c] * Srow[c];
  Tm[idx] = s;
}

// ---------------------------------------------------------------------------
// K3b: per (b,head): G = Wk S Wq^T, norms from diagonals, softmax -> attn
// ---------------------------------------------------------------------------
__global__ __launch_bounds__(256) void k3_attn(const float* __restrict__ Tm,
                                               const float* __restrict__ Wk,
                                               const float* __restrict__ Wq,
                                               const float* __restrict__ resc,
                                               float* __restrict__ attn) {
  const int blk = blockIdx.x;  // 16 = b*8+h
  const int b = blk >> 3, h = blk & 7;
  const int tid = threadIdx.x, d = tid >> 4, e = tid & 15;
  const float* Tk = Tm + (size_t)(b * 2 + 0) * 16384;
  const float* Tq = Tm + (size_t)(b * 2 + 1) * 16384;

  const float* tkrow = Tk + (h * 16 + d) * 128;
  const float* wqrow = Wq + (h * 16 + e) * 128;
  float g = 0.f;
#pragma unroll 4
  for (int c = 0; c < 128; ++c) g += tkrow[c] * wqrow[c];

  __shared__ float sqk[16], sqq[16];
  if (e == 0) {
    const float* wkrow = Wk + (h * 16 + d) * 128;
    float s = 0.f;
    for (int c = 0; c < 128; ++c) s += tkrow[c] * wkrow[c];
    sqk[d] = s;
  }
  if (d == 0) {
    const float* tqrow = Tq + (h * 16 + e) * 128;
    float s = 0.f;
    for (int c = 0; c < 128; ++c) s += tqrow[c] * wqrow[c];
    sqq[e] = s;
  }
  __syncthreads();

  const float nk = fmaxf(sqrtf(fmaxf(sqk[d], 0.f)), 1e-12f);
  const float nq = fmaxf(sqrtf(fmaxf(sqq[e], 0.f)), 1e-12f);
  float pre = g / (nk * nq) * resc[h];

  float mx = pre;
#pragma unroll
  for (int m = 1; m < 16; m <<= 1) mx = fmaxf(mx, __shfl_xor(mx, m, 64));
  const float p = expf(pre - mx);
  float sum = p;
#pragma unroll
  for (int m = 1; m < 16; m <<= 1) sum += __shfl_xor(sum, m, 64);
  attn[blk * 256 + tid] = p / sum;
}

// ---------------------------------------------------------------------------
// K3c: P[b] = Wp * blockdiag(attn[b]) * Wv, stored as bf16 hi+lo pair.
// ---------------------------------------------------------------------------
__global__ __launch_bounds__(256) void k3_p(const float* __restrict__ attn,
                                            const float* __restrict__ Wp,
                                            const float* __restrict__ Wv,
                                            bf16_t* __restrict__ Phi,
                                            bf16_t* __restrict__ Plo) {
  const int blk = blockIdx.x;  // 256 = b*128 + row
  const int b = blk >> 7, rrow = blk & 127;
  const int tid = threadIdx.x;
  __shared__ float M[128];
  if (tid < 128) {
    const int h = tid >> 4, e = tid & 15;
    const float* A = attn + (size_t)(b * 8 + h) * 256;
    const float* wp = Wp + rrow * 128 + h * 16;
    float m = 0.f;
#pragma unroll
    for (int d = 0; d < 16; ++d) m += wp[d] * A[d * 16 + e];
    M[tid] = m;
  }
  __syncthreads();
  if (tid < 128) {
    const int c = tid;
    float p = 0.f;
#pragma unroll 4
    for (int j = 0; j < 128; ++j) p += M[j] * Wv[j * 128 + c];
    const bf16_t hi = (bf16_t)p;
    const size_t o = ((size_t)b << 14) + rrow * 128 + c;
    Phi[o] = hi;
    Plo[o] = (bf16_t)(p - (float)hi);
  }
}

// ---------------------------------------------------------------------------
// K4: out[b] = P_b * X_b + bp, fp32 out in native [b][c][s][h][w] layout.
// Precision: P = Phi+Plo, x = xhi+xlo (bf16 splits); 3 MFMAs recover ~fp32.
// ---------------------------------------------------------------------------
__global__ __launch_bounds__(256) void k4_out(const float* __restrict__ x,
                                              const bf16_t* __restrict__ Phi,
                                              const bf16_t* __restrict__ Plo,
                                              const float* __restrict__ bp,
                                              float* __restrict__ out) {
  const int blk = blockIdx.x;  // 768 = b*384 + token-group
  const int b = blk / 384, tg = blk % 384;
  const float* Xb = x + (size_t)b * CDIM * NTOK;
  const bf16_t* Ph = Phi + ((size_t)b << 14);
  const bf16_t* Pl = Plo + ((size_t)b << 14);
  float* Ob = out + (size_t)b * CDIM * NTOK;
  const int tid = threadIdx.x, wave = tid >> 6, lane = tid & 63;
  const int r = lane & 15, quad = lane >> 4;
  const int tok0 = tg * 128 + wave * 32;

  f32x4 acc[8][2];
#pragma unroll
  for (int m = 0; m < 8; ++m)
#pragma unroll
    for (int nb = 0; nb < 2; ++nb) acc[m][nb] = (f32x4){0.f, 0.f, 0.f, 0.f};

#pragma unroll
  for (int kb = 0; kb < 128; kb += 32) {
    bf16x8 ah[8], al[8];
#pragma unroll
    for (int m = 0; m < 8; ++m) {
      ah[m] = *(const bf16x8*)(Ph + (16 * m + r) * 128 + kb + quad * 8);
      al[m] = *(const bf16x8*)(Pl + (16 * m + r) * 128 + kb + quad * 8);
    }
#pragma unroll
    for (int nb = 0; nb < 2; ++nb) {
      const int n0 = tok0 + nb * 16;
      const float* base = Xb + (size_t)(kb + quad * 8) * NTOK + n0 + r;
      bf16x8 bh, bl;
#pragma unroll
      for (int i = 0; i < 8; ++i) {
        const float v = base[(size_t)i * NTOK];
        const bf16_t h = (bf16_t)v;
        bh[i] = h;
        bl[i] = (bf16_t)(v - (float)h);
      }
#pragma unroll
      for (int m = 0; m < 8; ++m) {
        acc[m][nb] = __builtin_amdgcn_mfma_f32_16x16x32_bf16(ah[m], bh, acc[m][nb], 0, 0, 0);
        acc[m][nb] = __builtin_amdgcn_mfma_f32_16x16x32_bf16(ah[m], bl, acc[m][nb], 0, 0, 0);
        acc[m][nb] = __builtin_amdgcn_mfma_f32_16x16x32_bf16(al[m], bh, acc[m][nb], 0, 0, 0);
      }
    }
  }

#pragma unroll
  for (int m = 0; m < 8; ++m) {
#pragma unroll
    for (int nb = 0; nb < 2; ++nb) {
      const int n0 = tok0 + nb * 16;
#pragma unroll
      for (int reg = 0; reg < 4; ++reg) {
        const int row = m * 16 + quad * 4 + reg;
        Ob[(size_t)row * NTOK + n0 + r] = acc[m][nb][reg] + bp[row];
      }
    }
  }
}

extern "C" void kernel_launch(void* const* d_in, const int* in_sizes, int n_in,
                              void* d_out, int out_size, void* d_ws, size_t ws_size,
                              hipStream_t stream) {
  const float* x    = (const float*)d_in[0];
  const float* Wq   = (const float*)d_in[1];
  const float* Wk   = (const float*)d_in[2];
  const float* Wv   = (const float*)d_in[3];
  const float* Wp   = (const float*)d_in[4];
  const float* bp   = (const float*)d_in[5];
  const float* resc = (const float*)d_in[6];
  float* out = (float*)d_out;

  char* ws = (char*)d_ws;
  float*  S    = (float*)(ws + 0);        // 131072 B
  float*  Tm   = (float*)(ws + 131072);   // 262144 B
  float*  attn = (float*)(ws + 393216);   //  16384 B
  bf16_t* Phi  = (bf16_t*)(ws + 409600);  //  65536 B
  bf16_t* Plo  = (bf16_t*)(ws + 475136);  //  65536 B
  const size_t small_end = 540672;
  const size_t part_bytes = (size_t)2 * CHUNKS * 16384 * sizeof(float);  // 24 MB
  // Partials: d_ws if big enough, else d_out (48 MB fp32; consumed by k2
  // before k4 overwrites with the real output).
  float* part = (ws_size >= small_end + part_bytes) ? (float*)(ws + small_end)
                                                    : (float*)d_out;

  k1_gram<<<2 * CHUNKS, 256, 0, stream>>>(x, part);
  k2_reduce<<<128, 256, 0, stream>>>(part, S);
  k3_t<<<256, 256, 0, stream>>>(S, Wk, Wq, Tm);
  k3_attn<<<16, 256, 0, stream>>>(Tm, Wk, Wq, resc, attn);
  k3_p<<<256, 256, 0, stream>>>(attn, Wp, Wv, Phi, Plo);
  k4_out<<<768, 256, 0, stream>>>(x, Phi, Plo, bp, out);
}